// Round 3
// baseline (4237.051 us; speedup 1.0000x reference)
//
#include <hip/hip_runtime.h>
#include <hip/hip_bf16.h>

// 4 stacked LSTM layers (512->64, 64->64, 64->6, 6->6) + FC(6->6).
// B=64, T=1024, M = B*T = 65536.
//
// R2: scan64_sw — ONE WAVE per batch element, zero barriers (R1's cross-wave
//     lgkm-barrier scan was nondeterministic under timing). Lane u owns unit
//     u; all 256 W_hh weights for the unit live in VGPRs; h broadcast via
//     in-wave LDS round-trip with an lgkm-only waitcnt (single wave => no
//     s_barrier needed => no race possible). pk_fma via float2 vectors.

#define B_SZ 64
#define T_SZ 1024
#define M_SZ (B_SZ * T_SZ)

typedef float v2f __attribute__((ext_vector_type(2)));
typedef float v4f __attribute__((ext_vector_type(4)));

__device__ __forceinline__ float sigm_f(float x) {
    return 1.0f / (1.0f + __expf(-x));
}
__device__ __forceinline__ float tanh_f(float x) {
    return 2.0f / (1.0f + __expf(-2.0f * x)) - 1.0f;
}

__device__ __forceinline__ v2f fma2(v2f a, v2f b, v2f c) {
#if __has_builtin(__builtin_elementwise_fma)
    return __builtin_elementwise_fma(a, b, c);
#else
    v2f r; r.x = fmaf(a.x, b.x, c.x); r.y = fmaf(a.y, b.y, c.y); return r;
#endif
}

// wait for own LDS ops only (keeps global prefetch loads in flight);
// single-wave block => no s_barrier needed for LDS visibility.
__device__ __forceinline__ void lds_wait() {
    __asm__ __volatile__("s_waitcnt lgkmcnt(0)" ::: "memory");
}

// ---------------- input-projection GEMM, G=256 gates, D in {512, 64} -------
template <int D>
__global__ __launch_bounds__(256) void gemm_ih(const float* __restrict__ X,
                                               const float* __restrict__ W,
                                               const float* __restrict__ bias,
                                               float* __restrict__ out) {
    const int m0 = blockIdx.x * 16;
    const int g  = threadIdx.x;
    __shared__ __align__(16) float As[16 * D];
    for (int idx = g; idx < 16 * D; idx += 256) {
        As[idx] = X[(size_t)(m0 + idx / D) * D + (idx % D)];
    }
    __syncthreads();
    float acc[16];
    const float bg = bias[g];
#pragma unroll
    for (int m = 0; m < 16; ++m) acc[m] = bg;
    const float* Wg = W + (size_t)g * D;
    for (int k = 0; k < D; k += 4) {
        const float4 wv = *(const float4*)&Wg[k];
#pragma unroll
        for (int m = 0; m < 16; ++m) {
            const float4 av = *(const float4*)&As[m * D + k];
            acc[m] += av.x * wv.x + av.y * wv.y + av.z * wv.z + av.w * wv.w;
        }
    }
#pragma unroll
    for (int m = 0; m < 16; ++m) out[(size_t)(m0 + m) * 256 + g] = acc[m];
}

// ---------------- generic small GEMM (thread per output element) -----------
__global__ void gemm_naive(const float* __restrict__ X, const float* __restrict__ W,
                           const float* __restrict__ bias, float* __restrict__ out,
                           int M, int D, int G) {
    const int idx = blockIdx.x * 256 + threadIdx.x;
    if (idx >= M * G) return;
    const int m = idx / G, g = idx % G;
    float acc = bias[g];
    const float* xr = X + (size_t)m * D;
    const float* wr = W + (size_t)g * D;
    for (int k = 0; k < D; ++k) acc += xr[k] * wr[k];
    out[idx] = acc;
}

// ---------------- LSTM scan H=64, single wave per batch ---------------------
// Lane u (0..63) owns hidden unit u. Weights for all 4 gates of unit u in
// VGPRs (256 floats -> 128 v2f). h broadcast via LDS within the wave only.
__global__ __launch_bounds__(64, 1) void scan64_sw(const float* __restrict__ xg,
                                                   const float* __restrict__ whh,
                                                   float* __restrict__ hout) {
    const int b = blockIdx.x;
    const int u = threadIdx.x;              // unit id == lane id
    __shared__ __align__(16) float h_s[64];

    // w2[g][2*k4], w2[g][2*k4+1] = whh[(g*64+u)*64 + k4*4 .. +3]
    v2f w2[4][32];
#pragma unroll
    for (int g = 0; g < 4; ++g) {
        const float* wr = whh + (size_t)(g * 64 + u) * 64;
#pragma unroll
        for (int k4 = 0; k4 < 16; ++k4) {
            const v4f t = *(const v4f*)(wr + k4 * 4);
            w2[g][2 * k4]     = t.xy;
            w2[g][2 * k4 + 1] = t.zw;
        }
    }

    h_s[u] = 0.0f;
    lds_wait();

    const float* xgb = xg + (size_t)b * T_SZ * 256;
    float xv[4][4];
#pragma unroll
    for (int s = 0; s < 4; ++s)
#pragma unroll
        for (int g = 0; g < 4; ++g) xv[s][g] = xgb[s * 256 + g * 64 + u];

    float c = 0.0f;
    float* hrow = hout + (size_t)b * T_SZ * 64;

    for (int t = 0; t < T_SZ; ++t) {
        const int s = t & 3;
        v2f acc0, acc1, acc2, acc3;
        acc0.x = xv[s][0]; acc0.y = 0.0f;
        acc1.x = xv[s][1]; acc1.y = 0.0f;
        acc2.x = xv[s][2]; acc2.y = 0.0f;
        acc3.x = xv[s][3]; acc3.y = 0.0f;

        const v4f* hb = (const v4f*)h_s;
#pragma unroll
        for (int k4 = 0; k4 < 16; ++k4) {
            const v4f hv = hb[k4];
            const v2f hlo = hv.xy, hhi = hv.zw;
            acc0 = fma2(w2[0][2 * k4], hlo, acc0);
            acc1 = fma2(w2[1][2 * k4], hlo, acc1);
            acc2 = fma2(w2[2][2 * k4], hlo, acc2);
            acc3 = fma2(w2[3][2 * k4], hlo, acc3);
            acc0 = fma2(w2[0][2 * k4 + 1], hhi, acc0);
            acc1 = fma2(w2[1][2 * k4 + 1], hhi, acc1);
            acc2 = fma2(w2[2][2 * k4 + 1], hhi, acc2);
            acc3 = fma2(w2[3][2 * k4 + 1], hhi, acc3);
        }

        // prefetch xg for t+4 (vmcnt, untouched by lds_wait)
        {
            const int tp = (t + 4 < T_SZ) ? (t + 4) : (T_SZ - 1);
#pragma unroll
            for (int g = 0; g < 4; ++g)
                xv[s][g] = xgb[(size_t)tp * 256 + g * 64 + u];
        }

        const float iv = sigm_f(acc0.x + acc0.y);
        const float fv = sigm_f(acc1.x + acc1.y);
        const float gv = tanh_f(acc2.x + acc2.y);
        const float ov = sigm_f(acc3.x + acc3.y);
        c = fv * c + iv * gv;
        const float h = ov * tanh_f(c);

        hrow[t * 64 + u] = h;
        h_s[u] = h;
        lds_wait();        // own ds_write complete; lockstep wave => visible
    }
}

// ---------------- fused L3 + L4 + FC, one wave per batch --------------------
// lanes 0..5  : layer-3 unit u (input = precomputed xg3, recurrent over h3)
// lanes 6..11 : layer-4 unit u, pipelined 1 step behind (computes its own
//               input projection from h3[t-1]; input dim is 6)
// FC(6->6) folded in. No LDS, no barriers — all exchange via __shfl.
__global__ __launch_bounds__(64) void scan66(const float* __restrict__ xg3,
                                             const float* __restrict__ whh3,
                                             const float* __restrict__ wih4,
                                             const float* __restrict__ whh4,
                                             const float* __restrict__ b4,
                                             const float* __restrict__ fcw,
                                             const float* __restrict__ fcb,
                                             float* __restrict__ out) {
    const int b    = blockIdx.x;
    const int lane = threadIdx.x & 63;
    const bool is_l4 = (lane >= 6 && lane < 12);
    const int u = is_l4 ? (lane - 6) : (lane < 6 ? lane : 0);

    float w[4][12];
#pragma unroll
    for (int g = 0; g < 4; ++g) {
#pragma unroll
        for (int k = 0; k < 6; ++k) {
            const float wl3  = whh3[(g * 6 + u) * 6 + k];
            const float wl4i = wih4[(g * 6 + u) * 6 + k];
            const float wl4h = whh4[(g * 6 + u) * 6 + k];
            w[g][k]     = is_l4 ? wl4i : wl3;
            w[g][6 + k] = is_l4 ? wl4h : 0.0f;
        }
    }
    float bias[4], fw[6];
#pragma unroll
    for (int g = 0; g < 4; ++g) bias[g] = is_l4 ? b4[g * 6 + u] : 0.0f;
#pragma unroll
    for (int k = 0; k < 6; ++k) fw[k] = fcw[u * 6 + k];
    const float fb = fcb[u];

    const float* xgb = xg3 + (size_t)b * T_SZ * 24;
    float xv[4][4];
#pragma unroll
    for (int s = 0; s < 4; ++s)
#pragma unroll
        for (int g = 0; g < 4; ++g) xv[s][g] = xgb[s * 24 + g * 6 + u];

    float* outb = out + (size_t)b * T_SZ * 6;
    float h_own = 0.0f, c = 0.0f;

    for (int t4 = 0; t4 < T_SZ + 4; t4 += 4) {
#pragma unroll
        for (int s = 0; s < 4; ++s) {
            const int t = t4 + s;
            const float v0 = __shfl(h_own, 0),  v1 = __shfl(h_own, 1);
            const float v2 = __shfl(h_own, 2),  v3 = __shfl(h_own, 3);
            const float v4 = __shfl(h_own, 4),  v5 = __shfl(h_own, 5);
            const float v6 = __shfl(h_own, 6),  v7 = __shfl(h_own, 7);
            const float v8 = __shfl(h_own, 8),  v9 = __shfl(h_own, 9);
            const float v10 = __shfl(h_own, 10), v11 = __shfl(h_own, 11);

            if (is_l4 && t >= 2 && t < T_SZ + 2) {
                outb[(size_t)(t - 2) * 6 + u] =
                    fb + fw[0]*v6 + fw[1]*v7 + fw[2]*v8 +
                         fw[3]*v9 + fw[4]*v10 + fw[5]*v11;
            }

            float p[4];
#pragma unroll
            for (int g = 0; g < 4; ++g) {
                float a = is_l4 ? bias[g] : xv[s][g];
                a += w[g][0]*v0 + w[g][1]*v1 + w[g][2]*v2 +
                     w[g][3]*v3 + w[g][4]*v4 + w[g][5]*v5;
                a += w[g][6]*v6 + w[g][7]*v7 + w[g][8]*v8 +
                     w[g][9]*v9 + w[g][10]*v10 + w[g][11]*v11;
                p[g] = a;
            }
            {
                const int tp = (t + 4 < T_SZ) ? (t + 4) : (T_SZ - 1);
#pragma unroll
                for (int g = 0; g < 4; ++g)
                    xv[s][g] = xgb[(size_t)tp * 24 + g * 6 + u];
            }
            const float iv = sigm_f(p[0]);
            const float fv = sigm_f(p[1]);
            const float gv = tanh_f(p[2]);
            const float ov = sigm_f(p[3]);
            const float en = (is_l4 && t == 0) ? 0.0f : 1.0f;
            c = en * (fv * c + iv * gv);
            h_own = en * (ov * tanh_f(c));
        }
    }
}

extern "C" void kernel_launch(void* const* d_in, const int* in_sizes, int n_in,
                              void* d_out, int out_size, void* d_ws, size_t ws_size,
                              hipStream_t stream) {
    const float* x      = (const float*)d_in[0];
    const float* w1_ih0 = (const float*)d_in[1];
    const float* w1_hh0 = (const float*)d_in[2];
    const float* b1_0   = (const float*)d_in[3];
    const float* w1_ih1 = (const float*)d_in[4];
    const float* w1_hh1 = (const float*)d_in[5];
    const float* b1_1   = (const float*)d_in[6];
    const float* w2_ih0 = (const float*)d_in[7];
    const float* w2_hh0 = (const float*)d_in[8];
    const float* b2_0   = (const float*)d_in[9];
    const float* w2_ih1 = (const float*)d_in[10];
    const float* w2_hh1 = (const float*)d_in[11];
    const float* b2_1   = (const float*)d_in[12];
    const float* fc_w   = (const float*)d_in[13];
    const float* fc_b   = (const float*)d_in[14];
    float* out = (float*)d_out;

    const int M = M_SZ;
    float* xg = (float*)d_ws;                  // M*256 floats (reused as xg3)
    float* hA = xg + (size_t)M * 256;          // M*64
    float* hB = hA + (size_t)M * 64;           // M*64

    // L1: 512 -> 64
    gemm_ih<512><<<M / 16, 256, 0, stream>>>(x, w1_ih0, b1_0, xg);
    scan64_sw<<<B_SZ, 64, 0, stream>>>(xg, w1_hh0, hA);
    // L2: 64 -> 64
    gemm_ih<64><<<M / 16, 256, 0, stream>>>(hA, w1_ih1, b1_1, xg);
    scan64_sw<<<B_SZ, 64, 0, stream>>>(xg, w1_hh1, hB);
    // L3 input projection: 64 -> 24 gates
    gemm_naive<<<(M * 24 + 255) / 256, 256, 0, stream>>>(hB, w2_ih0, b2_0, xg, M, 64, 24);
    // L3 + L4 + FC fused
    scan66<<<B_SZ, 64, 0, stream>>>(xg, w2_hh0, w2_ih1, w2_hh1, b2_1, fc_w, fc_b, out);
}

// Round 4
// 2472.669 us; speedup vs baseline: 1.7136x; 1.7136x over previous
//
#include <hip/hip_runtime.h>
#include <hip/hip_bf16.h>

// 4 stacked LSTM layers (512->64, 64->64, 64->6, 6->6) + FC(6->6).
// B=64, T=1024, M = B*T = 65536.
//
// R3: fix weight residency. gfx950 caps ALU-addressable VGPRs at 256/lane;
//     R2's 256 fp32 weights/lane could not stay resident -> compiler
//     rematerialized the (uncoalesced) global weight loads every step
//     (VGPR_Count=152, ~3400 cyc/step). Fix: f16-packed weights (128 VGPRs)
//     + v_dot2_f32_f16 (2 MAC/inst), __launch_bounds__(64,1) so the backend
//     budget is the full 256. h exchanged as packed f16 through LDS with an
//     lgkm-only wait (single wave per block -> no barrier, no race).

#define B_SZ 64
#define T_SZ 1024
#define M_SZ (B_SZ * T_SZ)

typedef _Float16 h2 __attribute__((ext_vector_type(2)));
typedef _Float16 h8 __attribute__((ext_vector_type(8)));
typedef float    v4f __attribute__((ext_vector_type(4)));

__device__ __forceinline__ float sigm_f(float x) {
    return 1.0f / (1.0f + __expf(-x));
}
__device__ __forceinline__ float tanh_f(float x) {
    return 2.0f / (1.0f + __expf(-2.0f * x)) - 1.0f;
}

__device__ __forceinline__ float fdot2f(h2 a, h2 b, float c) {
#if __has_builtin(__builtin_amdgcn_fdot2)
    return __builtin_amdgcn_fdot2(a, b, c, false);
#else
    return c + (float)a.x * (float)b.x + (float)a.y * (float)b.y;
#endif
}

// wait own LDS ops only; single-wave block => lockstep => no s_barrier needed.
__device__ __forceinline__ void lds_wait() {
    __asm__ __volatile__("s_waitcnt lgkmcnt(0)" ::: "memory");
}

// ---------------- input-projection GEMM, G=256 gates, D in {512, 64} -------
template <int D>
__global__ __launch_bounds__(256) void gemm_ih(const float* __restrict__ X,
                                               const float* __restrict__ W,
                                               const float* __restrict__ bias,
                                               float* __restrict__ out) {
    const int m0 = blockIdx.x * 16;
    const int g  = threadIdx.x;
    __shared__ __align__(16) float As[16 * D];
    for (int idx = g; idx < 16 * D; idx += 256) {
        As[idx] = X[(size_t)(m0 + idx / D) * D + (idx % D)];
    }
    __syncthreads();
    float acc[16];
    const float bg = bias[g];
#pragma unroll
    for (int m = 0; m < 16; ++m) acc[m] = bg;
    const float* Wg = W + (size_t)g * D;
    for (int k = 0; k < D; k += 4) {
        const float4 wv = *(const float4*)&Wg[k];
#pragma unroll
        for (int m = 0; m < 16; ++m) {
            const float4 av = *(const float4*)&As[m * D + k];
            acc[m] += av.x * wv.x + av.y * wv.y + av.z * wv.z + av.w * wv.w;
        }
    }
#pragma unroll
    for (int m = 0; m < 16; ++m) out[(size_t)(m0 + m) * 256 + g] = acc[m];
}

// ---------------- generic small GEMM (thread per output element) -----------
__global__ void gemm_naive(const float* __restrict__ X, const float* __restrict__ W,
                           const float* __restrict__ bias, float* __restrict__ out,
                           int M, int D, int G) {
    const int idx = blockIdx.x * 256 + threadIdx.x;
    if (idx >= M * G) return;
    const int m = idx / G, g = idx % G;
    float acc = bias[g];
    const float* xr = X + (size_t)m * D;
    const float* wr = W + (size_t)g * D;
    for (int k = 0; k < D; ++k) acc += xr[k] * wr[k];
    out[idx] = acc;
}

// ---------------- LSTM scan H=64, single wave, f16 dot2 ---------------------
// Lane u owns unit u. Weights for the 4 gates of unit u live in VGPRs as
// 128 packed half2 (128 regs). h broadcast via LDS as packed f16.
__global__ __launch_bounds__(64, 1) void scan64_f16(const float* __restrict__ xg,
                                                    const float* __restrict__ whh,
                                                    float* __restrict__ hout) {
    const int b = blockIdx.x;
    const int u = threadIdx.x;
    __shared__ __align__(16) _Float16 h_sh[64];

    // w[g][k2] = {whh[(g*64+u)*64 + 2k2], whh[... + 2k2+1]} as f16
    h2 w[4][32];
#pragma unroll
    for (int g = 0; g < 4; ++g) {
        const float* wr = whh + (size_t)(g * 64 + u) * 64;
#pragma unroll
        for (int k2 = 0; k2 < 32; ++k2) {
            h2 p;
            p.x = (_Float16)wr[2 * k2];
            p.y = (_Float16)wr[2 * k2 + 1];
            w[g][k2] = p;
        }
    }

    h_sh[u] = (_Float16)0.0f;
    lds_wait();

    const float* xgb = xg + (size_t)b * T_SZ * 256;
    float xp[4][4];
#pragma unroll
    for (int s = 0; s < 4; ++s)
#pragma unroll
        for (int g = 0; g < 4; ++g) xp[s][g] = xgb[s * 256 + g * 64 + u];

    float c = 0.0f;
    float* hrow = hout + (size_t)b * T_SZ * 64;

    for (int t4 = 0; t4 < T_SZ; t4 += 4) {
#pragma unroll
        for (int s = 0; s < 4; ++s) {
            const int t = t4 + s;
            const h8* hb = (const h8*)h_sh;

            // two accumulator chains per gate (ILP), f32 accumulate
            float a0 = xp[s][0], b0 = 0.0f;
            float a1 = xp[s][1], b1 = 0.0f;
            float a2 = xp[s][2], b2 = 0.0f;
            float a3 = xp[s][3], b3 = 0.0f;
#pragma unroll
            for (int j = 0; j < 8; ++j) {
                const h8 hv = hb[j];           // broadcast ds_read_b128
                h2 p0, p1, p2, p3;
                p0.x = hv[0]; p0.y = hv[1];
                p1.x = hv[2]; p1.y = hv[3];
                p2.x = hv[4]; p2.y = hv[5];
                p3.x = hv[6]; p3.y = hv[7];
                a0 = fdot2f(w[0][4 * j + 0], p0, a0);
                b0 = fdot2f(w[0][4 * j + 1], p1, b0);
                a0 = fdot2f(w[0][4 * j + 2], p2, a0);
                b0 = fdot2f(w[0][4 * j + 3], p3, b0);
                a1 = fdot2f(w[1][4 * j + 0], p0, a1);
                b1 = fdot2f(w[1][4 * j + 1], p1, b1);
                a1 = fdot2f(w[1][4 * j + 2], p2, a1);
                b1 = fdot2f(w[1][4 * j + 3], p3, b1);
                a2 = fdot2f(w[2][4 * j + 0], p0, a2);
                b2 = fdot2f(w[2][4 * j + 1], p1, b2);
                a2 = fdot2f(w[2][4 * j + 2], p2, a2);
                b2 = fdot2f(w[2][4 * j + 3], p3, b2);
                a3 = fdot2f(w[3][4 * j + 0], p0, a3);
                b3 = fdot2f(w[3][4 * j + 1], p1, b3);
                a3 = fdot2f(w[3][4 * j + 2], p2, a3);
                b3 = fdot2f(w[3][4 * j + 3], p3, b3);
            }

            // prefetch xg for t+4 (vmcnt only; untouched by lds_wait)
            {
                const int tp = (t + 4 < T_SZ) ? (t + 4) : (T_SZ - 1);
#pragma unroll
                for (int g = 0; g < 4; ++g)
                    xp[s][g] = xgb[(size_t)tp * 256 + g * 64 + u];
            }

            const float iv = sigm_f(a0 + b0);
            const float fv = sigm_f(a1 + b1);
            const float gv = tanh_f(a2 + b2);
            const float ov = sigm_f(a3 + b3);
            c = fv * c + iv * gv;
            const float h = ov * tanh_f(c);

            hrow[t * 64 + u] = h;              // fp32 for the next gemm
            h_sh[u] = (_Float16)h;             // f16 for the recurrence
            lds_wait();
        }
    }
}

// ---------------- fused L3 + L4 + FC, one wave per batch --------------------
// lanes 0..5: layer-3 unit u; lanes 6..11: layer-4 unit u one step behind;
// FC folded into the h4 broadcast. Shuffle-only, no LDS, no barriers.
__global__ __launch_bounds__(64, 1) void scan66(const float* __restrict__ xg3,
                                                const float* __restrict__ whh3,
                                                const float* __restrict__ wih4,
                                                const float* __restrict__ whh4,
                                                const float* __restrict__ b4,
                                                const float* __restrict__ fcw,
                                                const float* __restrict__ fcb,
                                                float* __restrict__ out) {
    const int b    = blockIdx.x;
    const int lane = threadIdx.x & 63;
    const bool is_l4 = (lane >= 6 && lane < 12);
    const int u = is_l4 ? (lane - 6) : (lane < 6 ? lane : 0);

    float w[4][12];
#pragma unroll
    for (int g = 0; g < 4; ++g) {
#pragma unroll
        for (int k = 0; k < 6; ++k) {
            const float wl3  = whh3[(g * 6 + u) * 6 + k];
            const float wl4i = wih4[(g * 6 + u) * 6 + k];
            const float wl4h = whh4[(g * 6 + u) * 6 + k];
            w[g][k]     = is_l4 ? wl4i : wl3;
            w[g][6 + k] = is_l4 ? wl4h : 0.0f;
        }
    }
    float bias[4], fw[6];
#pragma unroll
    for (int g = 0; g < 4; ++g) bias[g] = is_l4 ? b4[g * 6 + u] : 0.0f;
#pragma unroll
    for (int k = 0; k < 6; ++k) fw[k] = fcw[u * 6 + k];
    const float fb = fcb[u];

    const float* xgb = xg3 + (size_t)b * T_SZ * 24;
    float xv[4][4];
#pragma unroll
    for (int s = 0; s < 4; ++s)
#pragma unroll
        for (int g = 0; g < 4; ++g) xv[s][g] = xgb[s * 24 + g * 6 + u];

    float* outb = out + (size_t)b * T_SZ * 6;
    float h_own = 0.0f, c = 0.0f;

    for (int t4 = 0; t4 < T_SZ + 4; t4 += 4) {
#pragma unroll
        for (int s = 0; s < 4; ++s) {
            const int t = t4 + s;
            const float v0 = __shfl(h_own, 0),  v1 = __shfl(h_own, 1);
            const float v2 = __shfl(h_own, 2),  v3 = __shfl(h_own, 3);
            const float v4 = __shfl(h_own, 4),  v5 = __shfl(h_own, 5);
            const float v6 = __shfl(h_own, 6),  v7 = __shfl(h_own, 7);
            const float v8 = __shfl(h_own, 8),  v9 = __shfl(h_own, 9);
            const float v10 = __shfl(h_own, 10), v11 = __shfl(h_own, 11);

            if (is_l4 && t >= 2 && t < T_SZ + 2) {
                outb[(size_t)(t - 2) * 6 + u] =
                    fb + fw[0]*v6 + fw[1]*v7 + fw[2]*v8 +
                         fw[3]*v9 + fw[4]*v10 + fw[5]*v11;
            }

            float p[4];
#pragma unroll
            for (int g = 0; g < 4; ++g) {
                float a = is_l4 ? bias[g] : xv[s][g];
                a += w[g][0]*v0 + w[g][1]*v1 + w[g][2]*v2 +
                     w[g][3]*v3 + w[g][4]*v4 + w[g][5]*v5;
                a += w[g][6]*v6 + w[g][7]*v7 + w[g][8]*v8 +
                     w[g][9]*v9 + w[g][10]*v10 + w[g][11]*v11;
                p[g] = a;
            }
            {
                const int tp = (t + 4 < T_SZ) ? (t + 4) : (T_SZ - 1);
#pragma unroll
                for (int g = 0; g < 4; ++g)
                    xv[s][g] = xgb[(size_t)tp * 24 + g * 6 + u];
            }
            const float iv = sigm_f(p[0]);
            const float fv = sigm_f(p[1]);
            const float gv = tanh_f(p[2]);
            const float ov = sigm_f(p[3]);
            const float en = (is_l4 && t == 0) ? 0.0f : 1.0f;
            c = en * (fv * c + iv * gv);
            h_own = en * (ov * tanh_f(c));
        }
    }
}

extern "C" void kernel_launch(void* const* d_in, const int* in_sizes, int n_in,
                              void* d_out, int out_size, void* d_ws, size_t ws_size,
                              hipStream_t stream) {
    const float* x      = (const float*)d_in[0];
    const float* w1_ih0 = (const float*)d_in[1];
    const float* w1_hh0 = (const float*)d_in[2];
    const float* b1_0   = (const float*)d_in[3];
    const float* w1_ih1 = (const float*)d_in[4];
    const float* w1_hh1 = (const float*)d_in[5];
    const float* b1_1   = (const float*)d_in[6];
    const float* w2_ih0 = (const float*)d_in[7];
    const float* w2_hh0 = (const float*)d_in[8];
    const float* b2_0   = (const float*)d_in[9];
    const float* w2_ih1 = (const float*)d_in[10];
    const float* w2_hh1 = (const float*)d_in[11];
    const float* b2_1   = (const float*)d_in[12];
    const float* fc_w   = (const float*)d_in[13];
    const float* fc_b   = (const float*)d_in[14];
    float* out = (float*)d_out;

    const int M = M_SZ;
    float* xg = (float*)d_ws;                  // M*256 floats (reused as xg3)
    float* hA = xg + (size_t)M * 256;          // M*64
    float* hB = hA + (size_t)M * 64;           // M*64

    // L1: 512 -> 64
    gemm_ih<512><<<M / 16, 256, 0, stream>>>(x, w1_ih0, b1_0, xg);
    scan64_f16<<<B_SZ, 64, 0, stream>>>(xg, w1_hh0, hA);
    // L2: 64 -> 64
    gemm_ih<64><<<M / 16, 256, 0, stream>>>(hA, w1_ih1, b1_1, xg);
    scan64_f16<<<B_SZ, 64, 0, stream>>>(xg, w1_hh1, hB);
    // L3 input projection: 64 -> 24 gates
    gemm_naive<<<(M * 24 + 255) / 256, 256, 0, stream>>>(hB, w2_ih0, b2_0, xg, M, 64, 24);
    // L3 + L4 + FC fused
    scan66<<<B_SZ, 64, 0, stream>>>(xg, w2_hh0, w2_ih1, w2_hh1, b2_1, fc_w, fc_b, out);
}

// Round 5
// 1954.845 us; speedup vs baseline: 2.1675x; 1.2649x over previous
//
#include <hip/hip_runtime.h>
#include <hip/hip_bf16.h>

// 4 stacked LSTM layers (512->64, 64->64, 64->6, 6->6) + FC(6->6).
// B=64, T=1024, M = B*T = 65536.
//
// R4: MFMA f16 input-projection GEMMs. R3's fp32 vector gemm_ih<512> was
//     600 us (VALUBusy 62%, LDS-issue bound, MfmaUtil 0). New gemm_mfma:
//     64x256 tile/block, K-chunks of 32, X staged fp32->f16 in LDS (XOR
//     swizzle), W pre-converted to f16 (L2-resident), bias in acc init.
//     Scans unchanged from R3 (passed, off top-5).

#define B_SZ 64
#define T_SZ 1024
#define M_SZ (B_SZ * T_SZ)

typedef _Float16 h2   __attribute__((ext_vector_type(2)));
typedef _Float16 h8   __attribute__((ext_vector_type(8)));
typedef float    f32x4 __attribute__((ext_vector_type(4)));

__device__ __forceinline__ float sigm_f(float x) {
    return 1.0f / (1.0f + __expf(-x));
}
__device__ __forceinline__ float tanh_f(float x) {
    return 2.0f / (1.0f + __expf(-2.0f * x)) - 1.0f;
}

__device__ __forceinline__ float fdot2f(h2 a, h2 b, float c) {
#if __has_builtin(__builtin_amdgcn_fdot2)
    return __builtin_amdgcn_fdot2(a, b, c, false);
#else
    return c + (float)a.x * (float)b.x + (float)a.y * (float)b.y;
#endif
}

// wait own LDS ops only; single-wave block => lockstep => no s_barrier needed.
__device__ __forceinline__ void lds_wait() {
    __asm__ __volatile__("s_waitcnt lgkmcnt(0)" ::: "memory");
}

// ---------------- fp32 -> f16 converter (for W_ih weights) ------------------
__global__ __launch_bounds__(256) void f32_to_f16(const float* __restrict__ src,
                                                  _Float16* __restrict__ dst, int n) {
    const int i = blockIdx.x * 256 + threadIdx.x;
    if (i < n) dst[i] = (_Float16)src[i];
}

// ---------------- MFMA input-projection GEMM --------------------------------
// out[m, g] = bias[g] + sum_k X[m,k] * W[g,k], G = 256 gates, K in {512, 64}.
// Block: 256 threads (4 waves). Tile: 64 rows x 256 cols. Wave w covers cols
// w*64 .. w*64+63 as 4x4 mfma_f32_16x16x32_f16 fragments.
// A layout: lane holds A[m=lane&15][k=quad*8+j]; B: B[k=quad*8+j][n=lane&15];
// C/D: col=lane&15, row=quad*4+reg (verified layouts, dtype-independent).
template <int K>
__global__ __launch_bounds__(256) void gemm_mfma(const float* __restrict__ X,
                                                 const _Float16* __restrict__ W16,
                                                 const float* __restrict__ bias,
                                                 float* __restrict__ out) {
    const int m0   = blockIdx.x * 64;
    const int tid  = threadIdx.x;
    const int wv   = tid >> 6;
    const int lane = tid & 63;
    const int lh   = lane & 15;
    const int quad = lane >> 4;
    const int n0   = wv * 64;

    __shared__ __align__(16) _Float16 Als[64 * 32];   // 64 rows x 32 k (f16)

    f32x4 acc[4][4];
#pragma unroll
    for (int nt = 0; nt < 4; ++nt) {
        const float bg = bias[n0 + nt * 16 + lh];
#pragma unroll
        for (int mt = 0; mt < 4; ++mt) {
            acc[mt][nt].x = bg; acc[mt][nt].y = bg;
            acc[mt][nt].z = bg; acc[mt][nt].w = bg;
        }
    }

    // staging map: thread t covers row t>>2, k8-block t&3 (8 f16 = 16 B)
    const int srow = tid >> 2;
    const int sk8  = tid & 3;
    const int sdst = srow * 32 + ((sk8 ^ (srow & 3)) * 8);

    for (int k0 = 0; k0 < K; k0 += 32) {
        // global loads first (schedule ahead of barrier)
        const float* xr = X + (size_t)(m0 + srow) * K + k0 + sk8 * 8;
        const float4 a4 = ((const float4*)xr)[0];
        const float4 b4 = ((const float4*)xr)[1];
        h8 bfrag[4];
#pragma unroll
        for (int nt = 0; nt < 4; ++nt) {
            bfrag[nt] = *(const h8*)&W16[(size_t)(n0 + nt * 16 + lh) * K + k0 + quad * 8];
        }
        h8 hv;
        hv[0] = (_Float16)a4.x; hv[1] = (_Float16)a4.y;
        hv[2] = (_Float16)a4.z; hv[3] = (_Float16)a4.w;
        hv[4] = (_Float16)b4.x; hv[5] = (_Float16)b4.y;
        hv[6] = (_Float16)b4.z; hv[7] = (_Float16)b4.w;

        __syncthreads();                 // previous iter's reads done
        *(h8*)&Als[sdst] = hv;
        __syncthreads();                 // writes visible

        h8 afrag[4];
#pragma unroll
        for (int mt = 0; mt < 4; ++mt) {
            const int row = mt * 16 + lh;
            afrag[mt] = *(const h8*)&Als[row * 32 + ((quad ^ (row & 3)) * 8)];
        }
#pragma unroll
        for (int mt = 0; mt < 4; ++mt)
#pragma unroll
            for (int nt = 0; nt < 4; ++nt)
                acc[mt][nt] = __builtin_amdgcn_mfma_f32_16x16x32_f16(
                    afrag[mt], bfrag[nt], acc[mt][nt], 0, 0, 0);
    }

#pragma unroll
    for (int mt = 0; mt < 4; ++mt)
#pragma unroll
        for (int nt = 0; nt < 4; ++nt)
#pragma unroll
            for (int r = 0; r < 4; ++r)
                out[(size_t)(m0 + mt * 16 + quad * 4 + r) * 256 + n0 + nt * 16 + lh] =
                    acc[mt][nt][r];
}

// ---------------- generic small GEMM (thread per output element) -----------
__global__ void gemm_naive(const float* __restrict__ X, const float* __restrict__ W,
                           const float* __restrict__ bias, float* __restrict__ out,
                           int M, int D, int G) {
    const int idx = blockIdx.x * 256 + threadIdx.x;
    if (idx >= M * G) return;
    const int m = idx / G, g = idx % G;
    float acc = bias[g];
    const float* xr = X + (size_t)m * D;
    const float* wr = W + (size_t)g * D;
    for (int k = 0; k < D; ++k) acc += xr[k] * wr[k];
    out[idx] = acc;
}

// ---------------- LSTM scan H=64, single wave, f16 dot2 ---------------------
__global__ __launch_bounds__(64, 1) void scan64_f16(const float* __restrict__ xg,
                                                    const float* __restrict__ whh,
                                                    float* __restrict__ hout) {
    const int b = blockIdx.x;
    const int u = threadIdx.x;
    __shared__ __align__(16) _Float16 h_sh[64];

    h2 w[4][32];
#pragma unroll
    for (int g = 0; g < 4; ++g) {
        const float* wr = whh + (size_t)(g * 64 + u) * 64;
#pragma unroll
        for (int k2 = 0; k2 < 32; ++k2) {
            h2 p;
            p.x = (_Float16)wr[2 * k2];
            p.y = (_Float16)wr[2 * k2 + 1];
            w[g][k2] = p;
        }
    }

    h_sh[u] = (_Float16)0.0f;
    lds_wait();

    const float* xgb = xg + (size_t)b * T_SZ * 256;
    float xp[4][4];
#pragma unroll
    for (int s = 0; s < 4; ++s)
#pragma unroll
        for (int g = 0; g < 4; ++g) xp[s][g] = xgb[s * 256 + g * 64 + u];

    float c = 0.0f;
    float* hrow = hout + (size_t)b * T_SZ * 64;

    for (int t4 = 0; t4 < T_SZ; t4 += 4) {
#pragma unroll
        for (int s = 0; s < 4; ++s) {
            const int t = t4 + s;
            const h8* hb = (const h8*)h_sh;

            float a0 = xp[s][0], b0 = 0.0f;
            float a1 = xp[s][1], b1 = 0.0f;
            float a2 = xp[s][2], b2 = 0.0f;
            float a3 = xp[s][3], b3 = 0.0f;
#pragma unroll
            for (int j = 0; j < 8; ++j) {
                const h8 hv = hb[j];
                h2 p0, p1, p2, p3;
                p0.x = hv[0]; p0.y = hv[1];
                p1.x = hv[2]; p1.y = hv[3];
                p2.x = hv[4]; p2.y = hv[5];
                p3.x = hv[6]; p3.y = hv[7];
                a0 = fdot2f(w[0][4 * j + 0], p0, a0);
                b0 = fdot2f(w[0][4 * j + 1], p1, b0);
                a0 = fdot2f(w[0][4 * j + 2], p2, a0);
                b0 = fdot2f(w[0][4 * j + 3], p3, b0);
                a1 = fdot2f(w[1][4 * j + 0], p0, a1);
                b1 = fdot2f(w[1][4 * j + 1], p1, b1);
                a1 = fdot2f(w[1][4 * j + 2], p2, a1);
                b1 = fdot2f(w[1][4 * j + 3], p3, b1);
                a2 = fdot2f(w[2][4 * j + 0], p0, a2);
                b2 = fdot2f(w[2][4 * j + 1], p1, b2);
                a2 = fdot2f(w[2][4 * j + 2], p2, a2);
                b2 = fdot2f(w[2][4 * j + 3], p3, b2);
                a3 = fdot2f(w[3][4 * j + 0], p0, a3);
                b3 = fdot2f(w[3][4 * j + 1], p1, b3);
                a3 = fdot2f(w[3][4 * j + 2], p2, a3);
                b3 = fdot2f(w[3][4 * j + 3], p3, b3);
            }

            {
                const int tp = (t + 4 < T_SZ) ? (t + 4) : (T_SZ - 1);
#pragma unroll
                for (int g = 0; g < 4; ++g)
                    xp[s][g] = xgb[(size_t)tp * 256 + g * 64 + u];
            }

            const float iv = sigm_f(a0 + b0);
            const float fv = sigm_f(a1 + b1);
            const float gv = tanh_f(a2 + b2);
            const float ov = sigm_f(a3 + b3);
            c = fv * c + iv * gv;
            const float h = ov * tanh_f(c);

            hrow[t * 64 + u] = h;
            h_sh[u] = (_Float16)h;
            lds_wait();
        }
    }
}

// ---------------- fused L3 + L4 + FC, one wave per batch --------------------
__global__ __launch_bounds__(64, 1) void scan66(const float* __restrict__ xg3,
                                                const float* __restrict__ whh3,
                                                const float* __restrict__ wih4,
                                                const float* __restrict__ whh4,
                                                const float* __restrict__ b4,
                                                const float* __restrict__ fcw,
                                                const float* __restrict__ fcb,
                                                float* __restrict__ out) {
    const int b    = blockIdx.x;
    const int lane = threadIdx.x & 63;
    const bool is_l4 = (lane >= 6 && lane < 12);
    const int u = is_l4 ? (lane - 6) : (lane < 6 ? lane : 0);

    float w[4][12];
#pragma unroll
    for (int g = 0; g < 4; ++g) {
#pragma unroll
        for (int k = 0; k < 6; ++k) {
            const float wl3  = whh3[(g * 6 + u) * 6 + k];
            const float wl4i = wih4[(g * 6 + u) * 6 + k];
            const float wl4h = whh4[(g * 6 + u) * 6 + k];
            w[g][k]     = is_l4 ? wl4i : wl3;
            w[g][6 + k] = is_l4 ? wl4h : 0.0f;
        }
    }
    float bias[4], fw[6];
#pragma unroll
    for (int g = 0; g < 4; ++g) bias[g] = is_l4 ? b4[g * 6 + u] : 0.0f;
#pragma unroll
    for (int k = 0; k < 6; ++k) fw[k] = fcw[u * 6 + k];
    const float fb = fcb[u];

    const float* xgb = xg3 + (size_t)b * T_SZ * 24;
    float xv[4][4];
#pragma unroll
    for (int s = 0; s < 4; ++s)
#pragma unroll
        for (int g = 0; g < 4; ++g) xv[s][g] = xgb[s * 24 + g * 6 + u];

    float* outb = out + (size_t)b * T_SZ * 6;
    float h_own = 0.0f, c = 0.0f;

    for (int t4 = 0; t4 < T_SZ + 4; t4 += 4) {
#pragma unroll
        for (int s = 0; s < 4; ++s) {
            const int t = t4 + s;
            const float v0 = __shfl(h_own, 0),  v1 = __shfl(h_own, 1);
            const float v2 = __shfl(h_own, 2),  v3 = __shfl(h_own, 3);
            const float v4 = __shfl(h_own, 4),  v5 = __shfl(h_own, 5);
            const float v6 = __shfl(h_own, 6),  v7 = __shfl(h_own, 7);
            const float v8 = __shfl(h_own, 8),  v9 = __shfl(h_own, 9);
            const float v10 = __shfl(h_own, 10), v11 = __shfl(h_own, 11);

            if (is_l4 && t >= 2 && t < T_SZ + 2) {
                outb[(size_t)(t - 2) * 6 + u] =
                    fb + fw[0]*v6 + fw[1]*v7 + fw[2]*v8 +
                         fw[3]*v9 + fw[4]*v10 + fw[5]*v11;
            }

            float p[4];
#pragma unroll
            for (int g = 0; g < 4; ++g) {
                float a = is_l4 ? bias[g] : xv[s][g];
                a += w[g][0]*v0 + w[g][1]*v1 + w[g][2]*v2 +
                     w[g][3]*v3 + w[g][4]*v4 + w[g][5]*v5;
                a += w[g][6]*v6 + w[g][7]*v7 + w[g][8]*v8 +
                     w[g][9]*v9 + w[g][10]*v10 + w[g][11]*v11;
                p[g] = a;
            }
            {
                const int tp = (t + 4 < T_SZ) ? (t + 4) : (T_SZ - 1);
#pragma unroll
                for (int g = 0; g < 4; ++g)
                    xv[s][g] = xgb[(size_t)tp * 24 + g * 6 + u];
            }
            const float iv = sigm_f(p[0]);
            const float fv = sigm_f(p[1]);
            const float gv = tanh_f(p[2]);
            const float ov = sigm_f(p[3]);
            const float en = (is_l4 && t == 0) ? 0.0f : 1.0f;
            c = en * (fv * c + iv * gv);
            h_own = en * (ov * tanh_f(c));
        }
    }
}

extern "C" void kernel_launch(void* const* d_in, const int* in_sizes, int n_in,
                              void* d_out, int out_size, void* d_ws, size_t ws_size,
                              hipStream_t stream) {
    const float* x      = (const float*)d_in[0];
    const float* w1_ih0 = (const float*)d_in[1];
    const float* w1_hh0 = (const float*)d_in[2];
    const float* b1_0   = (const float*)d_in[3];
    const float* w1_ih1 = (const float*)d_in[4];
    const float* w1_hh1 = (const float*)d_in[5];
    const float* b1_1   = (const float*)d_in[6];
    const float* w2_ih0 = (const float*)d_in[7];
    const float* w2_hh0 = (const float*)d_in[8];
    const float* b2_0   = (const float*)d_in[9];
    const float* w2_ih1 = (const float*)d_in[10];
    const float* w2_hh1 = (const float*)d_in[11];
    const float* b2_1   = (const float*)d_in[12];
    const float* fc_w   = (const float*)d_in[13];
    const float* fc_b   = (const float*)d_in[14];
    float* out = (float*)d_out;

    const int M = M_SZ;
    float* xg = (float*)d_ws;                  // M*256 f32 (reused as xg3)
    float* hA = xg + (size_t)M * 256;          // M*64 f32
    float* hB = hA + (size_t)M * 64;           // M*64 f32
    _Float16* w16a = (_Float16*)(hB + (size_t)M * 64);  // 256*512 f16
    _Float16* w16b = w16a + 256 * 512;                  // 256*64  f16

    // W_ih fp32 -> f16 (tiny, L2-resident afterwards)
    f32_to_f16<<<(256 * 512 + 255) / 256, 256, 0, stream>>>(w1_ih0, w16a, 256 * 512);
    f32_to_f16<<<(256 * 64 + 255) / 256, 256, 0, stream>>>(w1_ih1, w16b, 256 * 64);

    // L1: 512 -> 64
    gemm_mfma<512><<<M / 64, 256, 0, stream>>>(x, w16a, b1_0, xg);
    scan64_f16<<<B_SZ, 64, 0, stream>>>(xg, w1_hh0, hA);
    // L2: 64 -> 64
    gemm_mfma<64><<<M / 64, 256, 0, stream>>>(hA, w16b, b1_1, xg);
    scan64_f16<<<B_SZ, 64, 0, stream>>>(xg, w1_hh1, hB);
    // L3 input projection: 64 -> 24 gates
    gemm_naive<<<(M * 24 + 255) / 256, 256, 0, stream>>>(hB, w2_ih0, b2_0, xg, M, 64, 24);
    // L3 + L4 + FC fused
    scan66<<<B_SZ, 64, 0, stream>>>(xg, w2_hh0, w2_ih1, w2_hh1, b2_1, fc_w, fc_b, out);
}

// Round 6
// 1761.678 us; speedup vs baseline: 2.4051x; 1.1096x over previous
//
#include <hip/hip_runtime.h>
#include <hip/hip_bf16.h>

// 4 stacked LSTM layers (512->64, 64->64, 64->6, 6->6) + FC(6->6).
// B=64, T=1024, M = B*T = 65536.
//
// R5: scan64_rl — h broadcast via v_readlane -> SGPRs (v_dot2 takes one SGPR
//     operand), replacing the LDS round-trip + asm lgkm waits entirely.
//     R4 evidence: VGPR_Count=88 < 128 weight regs -> weights were in AGPRs
//     (accvgpr_read per use) + LDS roundtrip ~= 1330 cyc/step. New structure:
//     zero LDS, zero inline asm, pure dataflow. scan66 gets the same
//     readlane treatment (12 ds_bpermute -> 12 readlane).

#define B_SZ 64
#define T_SZ 1024
#define M_SZ (B_SZ * T_SZ)

typedef _Float16 h2   __attribute__((ext_vector_type(2)));
typedef _Float16 h8   __attribute__((ext_vector_type(8)));
typedef float    f32x4 __attribute__((ext_vector_type(4)));

__device__ __forceinline__ float sigm_f(float x) {
    return 1.0f / (1.0f + __expf(-x));
}
__device__ __forceinline__ float tanh_f(float x) {
    return 2.0f / (1.0f + __expf(-2.0f * x)) - 1.0f;
}

__device__ __forceinline__ float fdot2f(h2 a, h2 b, float c) {
#if __has_builtin(__builtin_amdgcn_fdot2)
    return __builtin_amdgcn_fdot2(a, b, c, false);
#else
    return c + (float)a.x * (float)b.x + (float)a.y * (float)b.y;
#endif
}

// ---------------- fp32 -> f16 converter (for W_ih weights) ------------------
__global__ __launch_bounds__(256) void f32_to_f16(const float* __restrict__ src,
                                                  _Float16* __restrict__ dst, int n) {
    const int i = blockIdx.x * 256 + threadIdx.x;
    if (i < n) dst[i] = (_Float16)src[i];
}

// ---------------- MFMA input-projection GEMM --------------------------------
// out[m, g] = bias[g] + sum_k X[m,k] * W[g,k], G = 256 gates, K in {512, 64}.
template <int K>
__global__ __launch_bounds__(256) void gemm_mfma(const float* __restrict__ X,
                                                 const _Float16* __restrict__ W16,
                                                 const float* __restrict__ bias,
                                                 float* __restrict__ out) {
    const int m0   = blockIdx.x * 64;
    const int tid  = threadIdx.x;
    const int wv   = tid >> 6;
    const int lane = tid & 63;
    const int lh   = lane & 15;
    const int quad = lane >> 4;
    const int n0   = wv * 64;

    __shared__ __align__(16) _Float16 Als[64 * 32];   // 64 rows x 32 k (f16)

    f32x4 acc[4][4];
#pragma unroll
    for (int nt = 0; nt < 4; ++nt) {
        const float bg = bias[n0 + nt * 16 + lh];
#pragma unroll
        for (int mt = 0; mt < 4; ++mt) {
            acc[mt][nt].x = bg; acc[mt][nt].y = bg;
            acc[mt][nt].z = bg; acc[mt][nt].w = bg;
        }
    }

    const int srow = tid >> 2;
    const int sk8  = tid & 3;
    const int sdst = srow * 32 + ((sk8 ^ (srow & 3)) * 8);

    for (int k0 = 0; k0 < K; k0 += 32) {
        const float* xr = X + (size_t)(m0 + srow) * K + k0 + sk8 * 8;
        const float4 a4 = ((const float4*)xr)[0];
        const float4 b4 = ((const float4*)xr)[1];
        h8 bfrag[4];
#pragma unroll
        for (int nt = 0; nt < 4; ++nt) {
            bfrag[nt] = *(const h8*)&W16[(size_t)(n0 + nt * 16 + lh) * K + k0 + quad * 8];
        }
        h8 hv;
        hv[0] = (_Float16)a4.x; hv[1] = (_Float16)a4.y;
        hv[2] = (_Float16)a4.z; hv[3] = (_Float16)a4.w;
        hv[4] = (_Float16)b4.x; hv[5] = (_Float16)b4.y;
        hv[6] = (_Float16)b4.z; hv[7] = (_Float16)b4.w;

        __syncthreads();
        *(h8*)&Als[sdst] = hv;
        __syncthreads();

        h8 afrag[4];
#pragma unroll
        for (int mt = 0; mt < 4; ++mt) {
            const int row = mt * 16 + lh;
            afrag[mt] = *(const h8*)&Als[row * 32 + ((quad ^ (row & 3)) * 8)];
        }
#pragma unroll
        for (int mt = 0; mt < 4; ++mt)
#pragma unroll
            for (int nt = 0; nt < 4; ++nt)
                acc[mt][nt] = __builtin_amdgcn_mfma_f32_16x16x32_f16(
                    afrag[mt], bfrag[nt], acc[mt][nt], 0, 0, 0);
    }

#pragma unroll
    for (int mt = 0; mt < 4; ++mt)
#pragma unroll
        for (int nt = 0; nt < 4; ++nt)
#pragma unroll
            for (int r = 0; r < 4; ++r)
                out[(size_t)(m0 + mt * 16 + quad * 4 + r) * 256 + n0 + nt * 16 + lh] =
                    acc[mt][nt][r];
}

// ---------------- generic small GEMM (thread per output element) -----------
__global__ void gemm_naive(const float* __restrict__ X, const float* __restrict__ W,
                           const float* __restrict__ bias, float* __restrict__ out,
                           int M, int D, int G) {
    const int idx = blockIdx.x * 256 + threadIdx.x;
    if (idx >= M * G) return;
    const int m = idx / G, g = idx % G;
    float acc = bias[g];
    const float* xr = X + (size_t)m * D;
    const float* wr = W + (size_t)g * D;
    for (int k = 0; k < D; ++k) acc += xr[k] * wr[k];
    out[idx] = acc;
}

// ---------------- LSTM scan H=64: single wave, readlane broadcast -----------
// Lane u owns unit u: its 4 W_hh rows as 128 packed-f16 VGPRs, plus h[u],c[u].
// Per step: h (one f16 per lane) is paired with its DPP neighbor and pulled
// into 32 wave-uniform SGPRs via v_readlane; v_dot2_f32_f16 then uses
// (VGPR weight, SGPR h-pair) — no LDS, no barriers, no asm.
__global__ __launch_bounds__(64, 1) void scan64_rl(const float* __restrict__ xg,
                                                   const float* __restrict__ whh,
                                                   float* __restrict__ hout) {
    const int b = blockIdx.x;
    const int u = threadIdx.x;

    h2 w[4][32];
#pragma unroll
    for (int g = 0; g < 4; ++g) {
        const float* wr = whh + (size_t)(g * 64 + u) * 64;
#pragma unroll
        for (int k2 = 0; k2 < 32; ++k2) {
            h2 p;
            p.x = (_Float16)wr[2 * k2];
            p.y = (_Float16)wr[2 * k2 + 1];
            w[g][k2] = p;
        }
    }

    const float* xgb = xg + (size_t)b * T_SZ * 256;
    float xp[4][4];
#pragma unroll
    for (int s = 0; s < 4; ++s)
#pragma unroll
        for (int g = 0; g < 4; ++g) xp[s][g] = xgb[s * 256 + g * 64 + u];

    float c = 0.0f, h_own = 0.0f;
    float* hrow = hout + (size_t)b * T_SZ * 64;

    for (int t4 = 0; t4 < T_SZ; t4 += 4) {
#pragma unroll
        for (int s = 0; s < 4; ++s) {
            const int t = t4 + s;

            // pack {h[2i], h[2i+1]} into even lanes, then broadcast via SGPRs
            const _Float16 hf = (_Float16)h_own;
            const int hb = (int)__builtin_bit_cast(unsigned short, hf);
            const int nb = __builtin_amdgcn_update_dpp(0, hb, 0xB1, 0xF, 0xF, true);
            const int pk = hb | (nb << 16);     // even lane 2i: {h2i, h2i+1}

            float a0 = xp[s][0];
            float a1 = xp[s][1];
            float a2 = xp[s][2];
            float a3 = xp[s][3];
#pragma unroll
            for (int k2 = 0; k2 < 32; ++k2) {
                const int hs = __builtin_amdgcn_readlane(pk, 2 * k2);
                const h2 hp = __builtin_bit_cast(h2, hs);
                a0 = fdot2f(w[0][k2], hp, a0);
                a1 = fdot2f(w[1][k2], hp, a1);
                a2 = fdot2f(w[2][k2], hp, a2);
                a3 = fdot2f(w[3][k2], hp, a3);
            }

            // prefetch xg for t+4 (16 loads in flight steady-state)
            {
                const int tp = (t + 4 < T_SZ) ? (t + 4) : (T_SZ - 1);
#pragma unroll
                for (int g = 0; g < 4; ++g)
                    xp[s][g] = xgb[(size_t)tp * 256 + g * 64 + u];
            }

            const float iv = sigm_f(a0);
            const float fv = sigm_f(a1);
            const float gv = tanh_f(a2);
            const float ov = sigm_f(a3);
            c = fv * c + iv * gv;
            h_own = ov * tanh_f(c);

            hrow[t * 64 + u] = h_own;
        }
    }
}

// ---------------- fused L3 + L4 + FC, one wave per batch --------------------
// lanes 0..5: layer-3 unit u; lanes 6..11: layer-4 unit u one step behind;
// FC folded into the h4 broadcast. readlane broadcast, no LDS, no barriers.
__global__ __launch_bounds__(64, 1) void scan66(const float* __restrict__ xg3,
                                                const float* __restrict__ whh3,
                                                const float* __restrict__ wih4,
                                                const float* __restrict__ whh4,
                                                const float* __restrict__ b4,
                                                const float* __restrict__ fcw,
                                                const float* __restrict__ fcb,
                                                float* __restrict__ out) {
    const int b    = blockIdx.x;
    const int lane = threadIdx.x & 63;
    const bool is_l4 = (lane >= 6 && lane < 12);
    const int u = is_l4 ? (lane - 6) : (lane < 6 ? lane : 0);

    float w[4][12];
#pragma unroll
    for (int g = 0; g < 4; ++g) {
#pragma unroll
        for (int k = 0; k < 6; ++k) {
            const float wl3  = whh3[(g * 6 + u) * 6 + k];
            const float wl4i = wih4[(g * 6 + u) * 6 + k];
            const float wl4h = whh4[(g * 6 + u) * 6 + k];
            w[g][k]     = is_l4 ? wl4i : wl3;
            w[g][6 + k] = is_l4 ? wl4h : 0.0f;
        }
    }
    float bias[4], fw[6];
#pragma unroll
    for (int g = 0; g < 4; ++g) bias[g] = is_l4 ? b4[g * 6 + u] : 0.0f;
#pragma unroll
    for (int k = 0; k < 6; ++k) fw[k] = fcw[u * 6 + k];
    const float fb = fcb[u];

    const float* xgb = xg3 + (size_t)b * T_SZ * 24;
    float xv[4][4];
#pragma unroll
    for (int s = 0; s < 4; ++s)
#pragma unroll
        for (int g = 0; g < 4; ++g) xv[s][g] = xgb[s * 24 + g * 6 + u];

    float* outb = out + (size_t)b * T_SZ * 6;
    float h_own = 0.0f, c = 0.0f;

    for (int t4 = 0; t4 < T_SZ + 4; t4 += 4) {
#pragma unroll
        for (int s = 0; s < 4; ++s) {
            const int t = t4 + s;
            const int hbits = __builtin_bit_cast(int, h_own);
            float v[12];
#pragma unroll
            for (int i = 0; i < 12; ++i)
                v[i] = __builtin_bit_cast(float, __builtin_amdgcn_readlane(hbits, i));

            if (is_l4 && t >= 2 && t < T_SZ + 2) {
                outb[(size_t)(t - 2) * 6 + u] =
                    fb + fw[0]*v[6] + fw[1]*v[7] + fw[2]*v[8] +
                         fw[3]*v[9] + fw[4]*v[10] + fw[5]*v[11];
            }

            float p[4];
#pragma unroll
            for (int g = 0; g < 4; ++g) {
                float a = is_l4 ? bias[g] : xv[s][g];
#pragma unroll
                for (int k = 0; k < 12; ++k) a += w[g][k] * v[k];
                p[g] = a;
            }
            {
                const int tp = (t + 4 < T_SZ) ? (t + 4) : (T_SZ - 1);
#pragma unroll
                for (int g = 0; g < 4; ++g)
                    xv[s][g] = xgb[(size_t)tp * 24 + g * 6 + u];
            }
            const float iv = sigm_f(p[0]);
            const float fv = sigm_f(p[1]);
            const float gv = tanh_f(p[2]);
            const float ov = sigm_f(p[3]);
            const float en = (is_l4 && t == 0) ? 0.0f : 1.0f;
            c = en * (fv * c + iv * gv);
            h_own = en * (ov * tanh_f(c));
        }
    }
}

extern "C" void kernel_launch(void* const* d_in, const int* in_sizes, int n_in,
                              void* d_out, int out_size, void* d_ws, size_t ws_size,
                              hipStream_t stream) {
    const float* x      = (const float*)d_in[0];
    const float* w1_ih0 = (const float*)d_in[1];
    const float* w1_hh0 = (const float*)d_in[2];
    const float* b1_0   = (const float*)d_in[3];
    const float* w1_ih1 = (const float*)d_in[4];
    const float* w1_hh1 = (const float*)d_in[5];
    const float* b1_1   = (const float*)d_in[6];
    const float* w2_ih0 = (const float*)d_in[7];
    const float* w2_hh0 = (const float*)d_in[8];
    const float* b2_0   = (const float*)d_in[9];
    const float* w2_ih1 = (const float*)d_in[10];
    const float* w2_hh1 = (const float*)d_in[11];
    const float* b2_1   = (const float*)d_in[12];
    const float* fc_w   = (const float*)d_in[13];
    const float* fc_b   = (const float*)d_in[14];
    float* out = (float*)d_out;

    const int M = M_SZ;
    float* xg = (float*)d_ws;                  // M*256 f32 (reused as xg3)
    float* hA = xg + (size_t)M * 256;          // M*64 f32
    float* hB = hA + (size_t)M * 64;           // M*64 f32
    _Float16* w16a = (_Float16*)(hB + (size_t)M * 64);  // 256*512 f16
    _Float16* w16b = w16a + 256 * 512;                  // 256*64  f16

    f32_to_f16<<<(256 * 512 + 255) / 256, 256, 0, stream>>>(w1_ih0, w16a, 256 * 512);
    f32_to_f16<<<(256 * 64 + 255) / 256, 256, 0, stream>>>(w1_ih1, w16b, 256 * 64);

    // L1: 512 -> 64
    gemm_mfma<512><<<M / 64, 256, 0, stream>>>(x, w16a, b1_0, xg);
    scan64_rl<<<B_SZ, 64, 0, stream>>>(xg, w1_hh0, hA);
    // L2: 64 -> 64
    gemm_mfma<64><<<M / 64, 256, 0, stream>>>(hA, w16b, b1_1, xg);
    scan64_rl<<<B_SZ, 64, 0, stream>>>(xg, w1_hh1, hB);
    // L3 input projection: 64 -> 24 gates
    gemm_naive<<<(M * 24 + 255) / 256, 256, 0, stream>>>(hB, w2_ih0, b2_0, xg, M, 64, 24);
    // L3 + L4 + FC fused
    scan66<<<B_SZ, 64, 0, stream>>>(xg, w2_hh0, w2_ih1, w2_hh1, b2_1, fc_w, fc_b, out);
}